// Round 31
// baseline (63.457 us; speedup 1.0000x reference)
//
#include <hip/hip_runtime.h>
#include <utility>

#define D_DIM 256
#define WID   33
#define CEN   16
#define RACC  4                    // output rows per thread (wave = row-group)
#define XROWS (RACC + 2 * CEN)     // 36 x-rows read per thread per iter
#define RITER 16                   // output rows per iteration (4 waves x 4)
#define NI    8                    // iterations per block
#define CHUNK (RITER * NI)         // 128 output rows per block
#define RING  64                   // ring rows
#define PROL  48                   // prologue staged rows (= RITER + 32)
#define LROW  128                  // dwords per LDS row (256 bf16 = 512 B)

// R28-30 co-binding: LDS-issue/9x-redundancy (5.8 TB/s unique) == HBM roof
// (6.3) at only 8 waves/CU -> both pipes ~55%, latency exposed. Fix: bf16
// LDS tile (tolerance is bf16-grade: R11 passed with BOTH operands bf16,
// absmax 0.0625; here only x is quantized). Ring 64 rows x 512B = 32 KB ->
// 4 blocks/CU = 16 waves/CU, LDS bytes halved. Reg-staged T14 split (DMA
// can't convert): loads issued phase-1, cvt+ds_write after compute, slot
// sets disjoint mod 64 (proven R28 geometry).

typedef float f32x4 __attribute__((ext_vector_type(4)));

__device__ __forceinline__ float rdlane(float v, int l) {
    return __uint_as_float(__builtin_amdgcn_readlane(__float_as_uint(v), l));
}

__device__ __forceinline__ int clampN(int p, int N) {
    return p < 0 ? 0 : (p >= N ? N - 1 : p);
}

__device__ __forceinline__ f32x4 ld4(const float* p) {
    return *(const f32x4*)p;
}

__device__ __forceinline__ unsigned bfbits(float f) {
    __bf16 b = (__bf16)f;                       // RNE cvt (R11-proven path)
    return (unsigned)__builtin_bit_cast(unsigned short, b);
}

__device__ __forceinline__ uint2 pack4(f32x4 v) {
    uint2 r;
    r.x = (bfbits(v.y) << 16) | bfbits(v.x);
    r.y = (bfbits(v.w) << 16) | bfbits(v.z);
    return r;
}

__device__ __forceinline__ f32x4 unpack4(uint2 d) {
    f32x4 v;
    v.x = __uint_as_float(d.x << 16);
    v.y = __uint_as_float(d.x & 0xffff0000u);
    v.z = __uint_as_float(d.y << 16);
    v.w = __uint_as_float(d.y & 0xffff0000u);
    return v;
}

// prologue: wave stages rows wv*12 .. wv*12+11 into slots 0..47
template <size_t... Ss>
__device__ __forceinline__ void stage_prol(unsigned* xs,
                                           const float* __restrict__ xgl,
                                           int base0, int N, int wv, int lane2,
                                           std::index_sequence<Ss...>) {
    (([&] {
         const int s = wv * (PROL / 4) + (int)Ss;
         const int p = clampN(base0 + s, N);
         *(uint2*)(xs + s * LROW + lane2) = pack4(ld4(xgl + (size_t)p * D_DIM));
     }()),
     ...);
}

// iter staging, load half: rows base0 + PROL + 16m + (wv*4 + Ks)
template <size_t... Ks>
__device__ __forceinline__ void stage_load(f32x4 (&sv)[RACC],
                                           const float* __restrict__ xgl,
                                           int rowb, int N, int wv,
                                           std::index_sequence<Ks...>) {
    ((sv[Ks] = ld4(xgl + (size_t)clampN(rowb + wv * 4 + (int)Ks, N) * D_DIM)),
     ...);
}

// iter staging, write half: slot (48 + 16m + wv*4 + Ks) & 63
template <size_t... Ks>
__device__ __forceinline__ void stage_write(unsigned* xs, const f32x4 (&sv)[RACC],
                                            int slotb, int wv, int lane2,
                                            std::index_sequence<Ks...>) {
    ((*(uint2*)(xs + ((slotb + wv * 4 + (int)Ks) & (RING - 1)) * LROW + lane2) =
          pack4(sv[Ks])),
     ...);
}

template <size_t... Rs>
__device__ __forceinline__ void load_w(float (&w)[RACC],
                                       const float* __restrict__ smb,
                                       int nbase, int minl, int N,
                                       std::index_sequence<Rs...>) {
    ((w[Rs] = smb[(size_t)clampN(nbase + (int)Rs, N) * WID + minl]), ...);
}

template <size_t... Rs>
__device__ __forceinline__ void zero_bad_w(float (&w)[RACC], int n0w, int lane,
                                           int N, std::index_sequence<Rs...>) {
    ((w[Rs] = ((unsigned)(n0w + (int)Rs - CEN + lane) < (unsigned)N)
                  ? w[Rs] : 0.0f),
     ...);
}

template <int J, size_t... Rs>
__device__ __forceinline__ void consume_j(f32x4 (&acc)[RACC],
                                          const float (&w)[RACC], f32x4 xv,
                                          std::index_sequence<Rs...>) {
    (([&] {
         constexpr int r = (int)Rs;
         if constexpr (J - r >= 0 && J - r < WID) {
             const float ws = rdlane(w[r], J - r);
             acc[r].x = fmaf(xv.x, ws, acc[r].x);
             acc[r].y = fmaf(xv.y, ws, acc[r].y);
             acc[r].z = fmaf(xv.z, ws, acc[r].z);
             acc[r].w = fmaf(xv.w, ws, acc[r].w);
         }
     }()),
     ...);
}

// read rel-rows (16m + 4wv + Js) -> slots (16m + 4wv + Js) & 63
template <size_t... Js>
__device__ __forceinline__ void stream_rows(f32x4 (&acc)[RACC],
                                            const float (&w)[RACC],
                                            const unsigned* xs, int sbase,
                                            int lane2,
                                            std::index_sequence<Js...>) {
    (([&] {
         const int s = (sbase + (int)Js) & (RING - 1);
         const uint2 d = *(const uint2*)(xs + s * LROW + lane2);
         consume_j<(int)Js>(acc, w, unpack4(d),
                            std::make_index_sequence<RACC>{});
     }()),
     ...);
}

template <size_t... Rs>
__device__ __forceinline__ void store_all(const f32x4 (&acc)[RACC], float szv,
                                          float* __restrict__ ob,
                                          std::index_sequence<Rs...>) {
    (([&] {
         constexpr int r = (int)Rs;
         const float inv = __builtin_amdgcn_rcpf(fmaxf(rdlane(szv, r), 1e-6f));
         f32x4 o;
         o.x = acc[r].x * inv; o.y = acc[r].y * inv;
         o.z = acc[r].z * inv; o.w = acc[r].w * inv;
         *(f32x4*)(ob + (size_t)r * D_DIM) = o;
     }()),
     ...);
}

__device__ __forceinline__ void iter_body(
    unsigned* xs, const float* __restrict__ xgl, const float* __restrict__ smb,
    const float* __restrict__ szb, float* __restrict__ obl, int n0, int m,
    int N, int wv, int lane, int lane2, float (&wcur)[RACC],
    float (&wnxt)[RACC], float& szcur, float& sznxt, int minl) {
    // phase 1: issue next-tile global loads + next-iter weight/size prefetch
    f32x4 sv[RACC];
    const bool more = (m < NI - 1);
    if (more)
        stage_load(sv, xgl, n0 - CEN + PROL + RITER * m, N, wv,
                   std::make_index_sequence<RACC>{});
    __builtin_amdgcn_sched_barrier(0);
    const int n1 = n0 + RITER * (m + 1) + wv * RACC;
    load_w(wnxt, smb, n1, minl, N, std::make_index_sequence<RACC>{});
    sznxt = szb[clampN(n1 + (lane & 3), N)];
    __builtin_amdgcn_sched_barrier(0);

    // phase 2: compute current 16 rows (4 per wave) from the bf16 ring
    const int n0w = n0 + RITER * m + wv * RACC;
    if (n0w < CEN || n0w + RACC - 1 + CEN >= N)      // boundary iters only
        zero_bad_w(wcur, n0w, lane, N, std::make_index_sequence<RACC>{});

    f32x4 acc[RACC] = {};
    stream_rows(acc, wcur, xs, RITER * m + wv * RACC, lane2,
                std::make_index_sequence<XROWS>{});
    store_all(acc, szcur, obl + (size_t)n0w * D_DIM,
              std::make_index_sequence<RACC>{});

    // phase 3: cvt + LDS-write the staged rows (loads landed under compute);
    // write slots disjoint (mod 64) from this iter's read slots.
    if (more)
        stage_write(xs, sv, PROL + RITER * m, wv, lane2,
                    std::make_index_sequence<RACC>{});

    __syncthreads();   // full drain: spill-proof (R24: ~0 cost here)
}

__global__ __launch_bounds__(256) void local_enc_kernel(
    const float* __restrict__ x, const float* __restrict__ sizev,
    const float* __restrict__ sm, float* __restrict__ out, int N) {
    __shared__ unsigned xs[RING * LROW];   // 64 rows x 512 B = 32 KB

    // XCD swizzle: XCD k owns batch k, strips consecutive -> L2-local
    const int bid   = blockIdx.x;
    const int swz   = (bid & 7) * 128 + (bid >> 3);
    const int strip = swz & 127;
    const int b     = swz >> 7;
    const int n0    = strip * CHUNK;
    const int tid   = threadIdx.x;
    const int wv    = tid >> 6;            // 0..3 -> row-group
    const int lane  = tid & 63;
    const int lane4 = lane * 4;            // this thread's 4 columns
    const int lane2 = lane * 2;            // dword index within LDS row

    const size_t bN = (size_t)b * (size_t)N;
    const float* __restrict__ xgl = x + bN * D_DIM + lane4;
    const float* __restrict__ smb = sm + bN * WID;
    const float* __restrict__ szb = sizev + bN;
    float* __restrict__ obl       = out + bN * D_DIM + lane4;

    // prologue: stage first 48 rows (bf16) + load iter-0 weights/sizes
    stage_prol(xs, xgl, n0 - CEN, N, wv, lane2,
               std::make_index_sequence<PROL / 4>{});
    const int minl = (lane < WID) ? lane : (WID - 1);
    float wA[RACC], wB[RACC];
    float szA, szB;
    load_w(wA, smb, n0 + wv * RACC, minl, N, std::make_index_sequence<RACC>{});
    szA = szb[clampN(n0 + wv * RACC + (lane & 3), N)];
    __syncthreads();

#pragma unroll 1
    for (int mp = 0; mp < NI / 2; ++mp) {
        const int m0 = 2 * mp;
        iter_body(xs, xgl, smb, szb, obl, n0, m0, N, wv, lane, lane2,
                  wA, wB, szA, szB, minl);
        iter_body(xs, xgl, smb, szb, obl, n0, m0 + 1, N, wv, lane, lane2,
                  wB, wA, szB, szA, minl);
    }
}

extern "C" void kernel_launch(void* const* d_in, const int* in_sizes, int n_in,
                              void* d_out, int out_size, void* d_ws, size_t ws_size,
                              hipStream_t stream) {
    const float* x  = (const float*)d_in[0];
    const float* sz = (const float*)d_in[1];
    const float* sm = (const float*)d_in[2];
    float* out = (float*)d_out;

    const int B = 8;
    const int N = 16384;

    dim3 grid((N / CHUNK) * B, 1, 1);   // 128 x 8 = 1024 blocks, XCD-swizzled
    dim3 block(256, 1, 1);
    local_enc_kernel<<<grid, block, 0, stream>>>(x, sz, sm, out, N);
}

// Round 32
// 55.290 us; speedup vs baseline: 1.1477x; 1.1477x over previous
//
#include <hip/hip_runtime.h>
#include <utility>

#define D_DIM 256
#define WID   33
#define CEN   16
#define RACC  4                    // output rows per thread (per wave-group)
#define XROWS (RACC + 2 * CEN)     // 36 x-rows read per thread per iter
#define RITER 16                   // output rows per iteration (4 waves x 4)
#define NI    16                   // iterations per block
#define CHUNK (RITER * NI)         // 256 output rows per block
#define RING  64                   // ring rows = 64 KB LDS (2 blocks/CU)
#define PROL  48                   // prologue staged rows (= RITER + 32)

// R28 (59.5us, best) + ONE change: non-temporal output stores.
// Rationale: working set x134 + sm17 + out134 = 285MB > 256MB L3 -> the
// never-read output stream thrashes L3, evicting x (steady FETCH 83MB of
// re-fetch) and spilling all writes to HBM. NT stores keep out out of L3;
// the 151MB read set then fits L3 entirely -> FETCH -> ~0-30MB, read
// latency L3-class, HBM floor ~ the 131MB write stream.
// (R30 proved LDS-issue isn't the binder: 2.25->1.25 b128/elem was flat.)

typedef float f32x4 __attribute__((ext_vector_type(4)));

__device__ __forceinline__ float rdlane(float v, int l) {
    return __uint_as_float(__builtin_amdgcn_readlane(__float_as_uint(v), l));
}

__device__ __forceinline__ int clampN(int p, int N) {
    return p < 0 ? 0 : (p >= N ? N - 1 : p);
}

__device__ __forceinline__ f32x4 ld4(const float* p) {
    return *(const f32x4*)p;
}

__device__ __forceinline__ void dma_row(float* xs, int slot,
                                        const float* __restrict__ xlane,
                                        int row) {
    __builtin_amdgcn_global_load_lds(
        (const __attribute__((address_space(1))) void*)(xlane +
                                                        (size_t)row * D_DIM),
        (__attribute__((address_space(3))) void*)(xs + slot * D_DIM), 16, 0, 0);
}

template <size_t... Ss>
__device__ __forceinline__ void stage_prol(float* xs,
                                           const float* __restrict__ xlane,
                                           int base0, int N, int wv,
                                           std::index_sequence<Ss...>) {
    (([&] {
         const int s = wv * (PROL / 4) + (int)Ss;      // 12 rows per wave
         dma_row(xs, s, xlane, clampN(base0 + s, N));
     }()),
     ...);
}

// stage 16 rows (4 per wave): row n0+32+16m+k -> slot (48+16m+k) & 63
__device__ __forceinline__ void stage_iter(float* xs,
                                           const float* __restrict__ xlane,
                                           int base0, int m, int N, int wv) {
#pragma unroll
    for (int kk = 0; kk < 4; ++kk) {
        const int k = wv * 4 + kk;
        const int s = (PROL + RITER * m + k) & (RING - 1);
        dma_row(xs, s, xlane, clampN(base0 + PROL + RITER * m + k, N));
    }
}

template <size_t... Rs>
__device__ __forceinline__ void load_w(float (&w)[RACC],
                                       const float* __restrict__ smb,
                                       int nbase, int minl, int N,
                                       std::index_sequence<Rs...>) {
    ((w[Rs] = smb[(size_t)clampN(nbase + (int)Rs, N) * WID + minl]), ...);
}

template <size_t... Rs>
__device__ __forceinline__ void zero_bad_w(float (&w)[RACC], int n0w, int lane,
                                           int N, std::index_sequence<Rs...>) {
    ((w[Rs] = ((unsigned)(n0w + (int)Rs - CEN + lane) < (unsigned)N)
                  ? w[Rs] : 0.0f),
     ...);
}

template <int J, size_t... Rs>
__device__ __forceinline__ void consume_j(f32x4 (&acc)[RACC],
                                          const float (&w)[RACC], f32x4 xv,
                                          std::index_sequence<Rs...>) {
    (([&] {
         constexpr int r = (int)Rs;
         if constexpr (J - r >= 0 && J - r < WID) {
             const float ws = rdlane(w[r], J - r);
             acc[r].x = fmaf(xv.x, ws, acc[r].x);
             acc[r].y = fmaf(xv.y, ws, acc[r].y);
             acc[r].z = fmaf(xv.z, ws, acc[r].z);
             acc[r].w = fmaf(xv.w, ws, acc[r].w);
         }
     }()),
     ...);
}

// read row (16m + 4wv - 16 + Js) -> slot (16m + 4wv + Js) & 63
template <size_t... Js>
__device__ __forceinline__ void stream_rows(f32x4 (&acc)[RACC],
                                            const float (&w)[RACC],
                                            const float* xs, int sbase,
                                            int lane4,
                                            std::index_sequence<Js...>) {
    (([&] {
         const int s = (sbase + (int)Js) & (RING - 1);
         const f32x4 xv = ld4(xs + s * D_DIM + lane4);
         consume_j<(int)Js>(acc, w, xv, std::make_index_sequence<RACC>{});
     }()),
     ...);
}

template <size_t... Rs>
__device__ __forceinline__ void store_all(const f32x4 (&acc)[RACC], float szv,
                                          float* __restrict__ ob,
                                          std::index_sequence<Rs...>) {
    (([&] {
         constexpr int r = (int)Rs;
         const float inv = __builtin_amdgcn_rcpf(fmaxf(rdlane(szv, r), 1e-6f));
         f32x4 o;
         o.x = acc[r].x * inv; o.y = acc[r].y * inv;
         o.z = acc[r].z * inv; o.w = acc[r].w * inv;
         __builtin_nontemporal_store(o, (f32x4*)(ob + (size_t)r * D_DIM));
     }()),
     ...);
}

__device__ __forceinline__ void iter_body(
    float* xs, const float* __restrict__ xlane, const float* __restrict__ smb,
    const float* __restrict__ szb, float* __restrict__ obl, int n0, int m,
    int N, int wv, int lane, int lane4, float (&wcur)[RACC],
    float (&wnxt)[RACC], float& szcur, float& sznxt, int minl) {
    // phase 1: issue next-tile DMA + next-iter weight/size prefetch
    if (m < NI - 1)
        stage_iter(xs, xlane, n0 - CEN, m, N, wv);
    __builtin_amdgcn_sched_barrier(0);
    const int n1 = n0 + RITER * (m + 1) + wv * RACC;
    load_w(wnxt, smb, n1, minl, N, std::make_index_sequence<RACC>{});
    sznxt = szb[clampN(n1 + (lane & 3), N)];
    __builtin_amdgcn_sched_barrier(0);

    // phase 2: compute current 16 rows (4 per wave) from the ring
    const int n0w = n0 + RITER * m + wv * RACC;
    if (n0w < CEN || n0w + RACC - 1 + CEN >= N)      // boundary iters only
        zero_bad_w(wcur, n0w, lane, N, std::make_index_sequence<RACC>{});

    f32x4 acc[RACC] = {};
    stream_rows(acc, wcur, xs, RITER * m + wv * RACC, lane4,
                std::make_index_sequence<XROWS>{});
    store_all(acc, szcur, obl + (size_t)n0w * D_DIM,
              std::make_index_sequence<RACC>{});

    __syncthreads();   // full drain: spill-proof, ~0 cost here (R24)
}

__global__ __launch_bounds__(256) void local_enc_kernel(
    const float* __restrict__ x, const float* __restrict__ sizev,
    const float* __restrict__ sm, float* __restrict__ out, int N) {
    __shared__ float xs[RING * D_DIM];     // 64 rows x 1KB = 64 KB

    // XCD swizzle: XCD k owns batch k, strips consecutive -> L2-local
    const int bid   = blockIdx.x;
    const int swz   = (bid & 7) * 64 + (bid >> 3);
    const int strip = swz & 63;
    const int b     = swz >> 6;
    const int n0    = strip * CHUNK;
    const int tid   = threadIdx.x;
    const int wv    = tid >> 6;            // 0..3 -> row-group
    const int lane  = tid & 63;
    const int lane4 = lane * 4;            // this thread's 4 columns

    const size_t bN = (size_t)b * (size_t)N;
    const float* __restrict__ xlane = x + bN * D_DIM + lane4;
    const float* __restrict__ smb   = sm + bN * WID;
    const float* __restrict__ szb   = sizev + bN;
    float* __restrict__ obl         = out + bN * D_DIM + lane4;

    // prologue: stage first 48 rows + load iter-0 weights/sizes
    stage_prol(xs, xlane, n0 - CEN, N, wv, std::make_index_sequence<PROL / 4>{});
    const int minl = (lane < WID) ? lane : (WID - 1);
    float wA[RACC], wB[RACC];
    float szA, szB;
    load_w(wA, smb, n0 + wv * RACC, minl, N, std::make_index_sequence<RACC>{});
    szA = szb[clampN(n0 + wv * RACC + (lane & 3), N)];
    __syncthreads();

#pragma unroll 1
    for (int mp = 0; mp < NI / 2; ++mp) {
        const int m0 = 2 * mp;
        iter_body(xs, xlane, smb, szb, obl, n0, m0, N, wv, lane, lane4,
                  wA, wB, szA, szB, minl);
        iter_body(xs, xlane, smb, szb, obl, n0, m0 + 1, N, wv, lane, lane4,
                  wB, wA, szB, szA, minl);
    }
}

extern "C" void kernel_launch(void* const* d_in, const int* in_sizes, int n_in,
                              void* d_out, int out_size, void* d_ws, size_t ws_size,
                              hipStream_t stream) {
    const float* x  = (const float*)d_in[0];
    const float* sz = (const float*)d_in[1];
    const float* sm = (const float*)d_in[2];
    float* out = (float*)d_out;

    const int B = 8;
    const int N = 16384;

    dim3 grid((N / CHUNK) * B, 1, 1);   // 64 x 8 = 512 blocks, XCD-swizzled
    dim3 block(256, 1, 1);
    local_enc_kernel<<<grid, block, 0, stream>>>(x, sz, sm, out, N);
}